// Round 1
// baseline (148.551 us; speedup 1.0000x reference)
//
#include <hip/hip_runtime.h>

// Problem constants (NeighborCooccurrenceEncoder): B=1024, SRC_L=DST_L=256, D=64
#define BATCH 1024
#define L 256
#define D 64
#define NIDS 10000          // ids in [0, 10000)
#define TABN 257            // possible count values 0..256

// ---------------------------------------------------------------------------
// Kernel 1: precompute MLP lookup table.
// tab[a][e] = b2[e] + sum_d relu(a*W1[d] + b1[d]) * W2[e][d],  a in [0,256]
// (einsum 'blcd,ed' => out[e] = sum_d h[d]*W2[e,d])
// Must be rebuilt every launch: d_ws is re-poisoned before each timed call.
// ---------------------------------------------------------------------------
__global__ void build_table_kernel(const float* __restrict__ W1,
                                   const float* __restrict__ b1,
                                   const float* __restrict__ W2,
                                   const float* __restrict__ b2,
                                   float* __restrict__ tab) {
    const int a = blockIdx.x;    // count value 0..256
    const int e = threadIdx.x;   // output channel 0..63
    const float af = (float)a;
    float acc = b2[e];
    #pragma unroll
    for (int d = 0; d < D; ++d) {
        float h = af * W1[d] + b1[d];   // W1 is (D,1): W1[d][0]
        h = h > 0.0f ? h : 0.0f;
        acc += h * W2[e * D + d];
    }
    tab[a * D + e] = acc;
}

// ---------------------------------------------------------------------------
// Kernel 2: per-batch histogram co-occurrence + table-gather output.
// One block per batch. LDS: two 16-bit-packed histograms (counts <= 256
// so the packed halves can never overflow into each other).
// ---------------------------------------------------------------------------
__global__ __launch_bounds__(256) void cooc_kernel(
        const int* __restrict__ src_ids,
        const int* __restrict__ dst_ids,
        const float* __restrict__ tab,
        float* __restrict__ out) {
    // 2 histograms x 5000 packed u32 = 40000 B; ids 2 KB; counts 2 KB
    __shared__ unsigned int hist[2][NIDS / 2];
    __shared__ int          ids[2 * L];
    __shared__ unsigned int cnts[2 * L];   // low16 = ch0 count, high16 = ch1 count

    const int b   = blockIdx.x;
    const int tid = threadIdx.x;

    // --- phase 1: zero histograms ---
    unsigned int* h = &hist[0][0];
    #pragma unroll
    for (int i = tid; i < NIDS; i += 256) h[i] = 0u;

    // load ids (tid indexes one src and one dst position; L == blockDim)
    const int sid = src_ids[b * L + tid];
    const int did = dst_ids[b * L + tid];
    ids[tid]     = sid;
    ids[L + tid] = did;
    __syncthreads();

    // --- phase 2: build histograms (LDS atomics, 16-bit packed) ---
    atomicAdd(&hist[0][sid >> 1], 1u << ((sid & 1) * 16));
    atomicAdd(&hist[1][did >> 1], 1u << ((did & 1) * 16));
    __syncthreads();

    // --- phase 3: per-position counts ---
    {
        // src position tid: [src_in_src, src_in_dst]
        int id = ids[tid];
        unsigned c0 = (hist[0][id >> 1] >> ((id & 1) * 16)) & 0xffffu;
        unsigned c1 = (hist[1][id >> 1] >> ((id & 1) * 16)) & 0xffffu;
        if (id == 0) { c0 = 0u; c1 = 0u; }
        cnts[tid] = c0 | (c1 << 16);
        // dst position tid: [dst_in_src, dst_in_dst] (summed, order irrelevant)
        id = ids[L + tid];
        unsigned d0 = (hist[0][id >> 1] >> ((id & 1) * 16)) & 0xffffu;
        unsigned d1 = (hist[1][id >> 1] >> ((id & 1) * 16)) & 0xffffu;
        if (id == 0) { d0 = 0u; d1 = 0u; }
        cnts[L + tid] = d0 | (d1 << 16);
    }
    __syncthreads();

    // --- phase 4: gather table rows, write output (float4 vectorized) ---
    // out layout: [src_feat (B,L,D) | dst_feat (B,L,D)], f32
    const float4* tab4 = (const float4*)tab;
    float4*       out4 = (float4*)out;
    const int q  = tid & 15;   // float4 slot within a 64-float row (D/4 = 16)
    const int pg = tid >> 4;   // 16 position-groups per block
    const int ROW4 = D / 4;    // 16

    #pragma unroll 4
    for (int p = pg; p < 2 * L; p += 16) {
        const unsigned cp = cnts[p];
        const unsigned c1 = cp & 0xffffu;
        const unsigned c2 = cp >> 16;
        const float4 v1 = tab4[c1 * ROW4 + q];
        const float4 v2 = tab4[c2 * ROW4 + q];
        float4 v;
        v.x = v1.x + v2.x; v.y = v1.y + v2.y;
        v.z = v1.z + v2.z; v.w = v1.w + v2.w;
        int off;
        if (p < L) {
            off = b * (L * ROW4) + p * ROW4 + q;                      // src_feat
        } else {
            off = BATCH * L * ROW4 + b * (L * ROW4) + (p - L) * ROW4 + q; // dst_feat
        }
        out4[off] = v;
    }
}

extern "C" void kernel_launch(void* const* d_in, const int* in_sizes, int n_in,
                              void* d_out, int out_size, void* d_ws, size_t ws_size,
                              hipStream_t stream) {
    const int*   src_ids = (const int*)d_in[0];
    const int*   dst_ids = (const int*)d_in[1];
    const float* W1      = (const float*)d_in[2];
    const float* b1      = (const float*)d_in[3];
    const float* W2      = (const float*)d_in[4];
    const float* b2      = (const float*)d_in[5];
    float*       out     = (float*)d_out;
    float*       tab     = (float*)d_ws;   // 257*64*4 = 65,792 B

    build_table_kernel<<<TABN, D, 0, stream>>>(W1, b1, W2, b2, tab);
    cooc_kernel<<<BATCH, 256, 0, stream>>>(src_ids, dst_ids, tab, out);
}